// Round 4
// baseline (592.800 us; speedup 1.0000x reference)
//
#include <hip/hip_runtime.h>
#include <hip/hip_bf16.h>

typedef unsigned short u16;
typedef __attribute__((ext_vector_type(8))) short short8;
typedef __attribute__((ext_vector_type(4))) float f32x4;

#define NE 131072

// ws layout in u16 elements (bf16 transposed weights, [n][k] row-major)
#define OFF_WA 0        // 4 x [256][256]
#define OFF_WB 262144   // 4 x [128][256]
#define OFF_WF 393216   // 4 x [128][128]  (block = k-slice of 128)
#define OFF_WE 458752   // [128][32]
#define OFF_WS 462848   // [128]

__device__ __forceinline__ float b2f(u16 v) {
    unsigned int u = ((unsigned int)v) << 16;
    float f;
    __builtin_memcpy(&f, &u, 4);
    return f;
}
__device__ __forceinline__ u16 f2b(float f) {
    __hip_bfloat16 h = __float2bfloat16(f);
    u16 u;
    __builtin_memcpy(&u, &h, 2);
    return u;
}
__device__ __forceinline__ short8 pack8(f32x4 a, f32x4 b) {
    short8 p;
    p[0] = (short)f2b(a.x); p[1] = (short)f2b(a.y);
    p[2] = (short)f2b(a.z); p[3] = (short)f2b(a.w);
    p[4] = (short)f2b(b.x); p[5] = (short)f2b(b.y);
    p[6] = (short)f2b(b.z); p[7] = (short)f2b(b.w);
    return p;
}

#define MFMA16(a, b, c) __builtin_amdgcn_mfma_f32_16x16x32_bf16(a, b, c, 0, 0, 0)

struct BiasP {
    const float* ba[4];
    const float* bb[4];
};

// LDS-tiled transpose prep: coalesced reads AND writes.
__global__ __launch_bounds__(256)
void prep_kernel(const float* __restrict__ W1a, const float* __restrict__ W2a,
                 const float* __restrict__ W3a, const float* __restrict__ W4a,
                 const float* __restrict__ W1b, const float* __restrict__ W2b,
                 const float* __restrict__ W3b, const float* __restrict__ W4b,
                 const float* __restrict__ Wf,  u16* __restrict__ ws) {
    __shared__ __align__(16) u16 T[64 * 80];

    const int y = blockIdx.y;
    const int t = threadIdx.x;
    const float* in;
    int K, N;
    if (y < 4)      { in = (y == 0) ? W1a : (y == 1) ? W2a : (y == 2) ? W3a : W4a; K = 256; N = 256; }
    else if (y < 8) { in = (y == 4) ? W1b : (y == 5) ? W2b : (y == 6) ? W3b : W4b; K = 256; N = 128; }
    else            { in = Wf; K = 545; N = 128; }

    const int ntilesN = N / 64;
    const int ktiles = (K + 63) / 64;
    const int kt = blockIdx.x / ntilesN;
    const int nt = blockIdx.x - kt * ntilesN;
    if (kt >= ktiles) return;
    const int kbase = kt * 64, nbase = nt * 64;

    {
        int tn = (t & 15) * 4;
        int tk = t >> 4;
        #pragma unroll
        for (int r = 0; r < 4; r++) {
            int k = kbase + tk + 16 * r;
            if (k < K) {
                float4 v = *(const float4*)(in + (size_t)k * N + nbase + tn);
                T[(tn + 0) * 80 + tk + 16 * r] = f2b(v.x);
                T[(tn + 1) * 80 + tk + 16 * r] = f2b(v.y);
                T[(tn + 2) * 80 + tk + 16 * r] = f2b(v.z);
                T[(tn + 3) * 80 + tk + 16 * r] = f2b(v.w);
            }
        }
    }
    __syncthreads();
    {
        int n = t >> 2;
        int kc = (t & 3) * 16;
        int n_out = nbase + n;
        const u16* src = &T[n * 80 + kc];
        if (y < 4) {
            u16* dst = ws + OFF_WA + y * 65536 + (size_t)n_out * 256 + kbase + kc;
            *(short8*)dst = *(const short8*)src;
            *(short8*)(dst + 8) = *(const short8*)(src + 8);
        } else if (y < 8) {
            u16* dst = ws + OFF_WB + (y - 4) * 32768 + (size_t)n_out * 256 + kbase + kc;
            *(short8*)dst = *(const short8*)src;
            *(short8*)(dst + 8) = *(const short8*)(src + 8);
        } else if (kbase < 512) {
            u16* dst = ws + OFF_WF + (kbase >> 7) * 16384 + (size_t)n_out * 128 + (kbase & 127) + kc;
            *(short8*)dst = *(const short8*)src;
            *(short8*)(dst + 8) = *(const short8*)(src + 8);
        } else {
            #pragma unroll
            for (int j = 0; j < 16; j++) {
                int k = kbase + kc + j;
                if (k < 545) {
                    u16 v = src[j];
                    if (k == 512)      ws[OFF_WS + n_out] = v;
                    else               ws[OFF_WE + n_out * 32 + (k - 513)] = v;
                }
            }
        }
    }
}

// 32 edges/block, 4 waves, ~51 KB LDS -> 3 blocks/CU (12 waves/CU).
// Weights: loaded DIRECTLY into VGPRs (no LDS staging, no asm waits) with a
// software-pipelined double buffer per stage; the compiler emits its own
// counted s_waitcnt vmcnt(N) before first use. G overlays Hs cols 0..127
// (extra BARRIER_B2 fences last H-read from the G-write).
// Barrier/hazard order per m:
//   A reads Xs/Xd, writes Hs | BARRIER_A | B reads Hs | BARRIER_B2 |
//   G-write (Hs cols<128)    | BARRIER_B | C reads G  | BARRIER_C (m<3) |
__global__ __launch_bounds__(256, 3)
void fused_kernel(const float* __restrict__ x, const int* __restrict__ ei,
                  const float* __restrict__ ea, const u16* __restrict__ ws,
                  BiasP bp, const float* __restrict__ bfp, float* __restrict__ out) {
    __shared__ __align__(16) u16 Xs[32][264];
    __shared__ __align__(16) u16 Xd[32][264];
    __shared__ __align__(16) u16 Hs[32][264];   // cols 0..127 double as G
    __shared__ float scos[32];

    const int t = threadIdx.x;
    const int wave = t >> 6;
    const int lane = t & 63;
    const int l15 = lane & 15;
    const int g = lane >> 4;
    const int e0 = blockIdx.x * 32;
    const f32x4 zero4 = {0.f, 0.f, 0.f, 0.f};
    const int colA = wave * 64;
    const int colC = wave * 32;

    // Hedge: detect int64 edge_index (sampled high words all zero) vs int32.
    bool idx64 = true;
    #pragma unroll
    for (int i = 1; i < 16; i += 2) { idx64 = idx64 && (ei[i] == 0); }

    // per-lane weight base pointers (fragment = 16B at [col][k-slot])
    const u16* pA = ws + OFF_WA + (size_t)(colA + l15) * 256 + g * 8;
    const u16* pB = ws + OFF_WB + (size_t)(colC + l15) * 256 + g * 8;
    const u16* pC = ws + OFF_WF + (size_t)(colC + l15) * 128 + g * 8;

    // preload A(m=0) kk=0,1 into regs; they ride under the gather latency
    short8 wfA[2][4];
    #pragma unroll
    for (int nt = 0; nt < 4; nt++) wfA[0][nt] = *(const short8*)(pA + nt * 4096);
    #pragma unroll
    for (int nt = 0; nt < 4; nt++) wfA[1][nt] = *(const short8*)(pA + nt * 4096 + 32);

    // ---- gather (f32 -> bf16 tiles) + cosine similarity in one pass ----
    {
        int edge = t >> 3;
        int c = t & 7;
        int pos = e0 + edge;
        int is = idx64 ? ei[2 * pos] : ei[pos];
        int id = idx64 ? ei[2 * (NE + pos)] : ei[NE + pos];
        const float* rs = x + (size_t)is * 256 + c * 32;
        const float* rd = x + (size_t)id * 256 + c * 32;
        float dot = 0.f, ss = 0.f, dd = 0.f;
        #pragma unroll
        for (int i = 0; i < 4; i++) {
            f32x4 s0 = *(const f32x4*)(rs + i * 8);
            f32x4 s1 = *(const f32x4*)(rs + i * 8 + 4);
            f32x4 d0 = *(const f32x4*)(rd + i * 8);
            f32x4 d1 = *(const f32x4*)(rd + i * 8 + 4);
            dot += s0.x * d0.x + s0.y * d0.y + s0.z * d0.z + s0.w * d0.w
                 + s1.x * d1.x + s1.y * d1.y + s1.z * d1.z + s1.w * d1.w;
            ss  += s0.x * s0.x + s0.y * s0.y + s0.z * s0.z + s0.w * s0.w
                 + s1.x * s1.x + s1.y * s1.y + s1.z * s1.z + s1.w * s1.w;
            dd  += d0.x * d0.x + d0.y * d0.y + d0.z * d0.z + d0.w * d0.w
                 + d1.x * d1.x + d1.y * d1.y + d1.z * d1.z + d1.w * d1.w;
            *(short8*)(&Xs[edge][c * 32 + i * 8]) = pack8(s0, s1);
            *(short8*)(&Xd[edge][c * 32 + i * 8]) = pack8(d0, d1);
        }
        dot += __shfl_xor(dot, 1); ss += __shfl_xor(ss, 1); dd += __shfl_xor(dd, 1);
        dot += __shfl_xor(dot, 2); ss += __shfl_xor(ss, 2); dd += __shfl_xor(dd, 2);
        dot += __shfl_xor(dot, 4); ss += __shfl_xor(ss, 4); dd += __shfl_xor(dd, 4);
        if (c == 0) {
            float ns = fmaxf(sqrtf(ss), 1e-8f);
            float nd = fmaxf(sqrtf(dd), 1e-8f);
            scos[edge] = dot / (ns * nd);
        }
    }
    __syncthreads();   // gather barrier: Xs/Xd/scos visible (drains preloads too)

    // ---- LDS read base pointers ----
    const u16* xsb0 = &Xs[l15][g * 8];      const u16* xsb1 = &Xs[16 + l15][g * 8];
    const u16* xdb0 = &Xd[l15][g * 8];      const u16* xdb1 = &Xd[16 + l15][g * 8];
    const u16* hgb0 = &Hs[l15][g * 8];      const u16* hgb1 = &Hs[16 + l15][g * 8];

    f32x4 Facc[2][2];
    #pragma unroll
    for (int a = 0; a < 2; a++) {
        #pragma unroll
        for (int b = 0; b < 2; b++) Facc[a][b] = zero4;
    }

    #pragma unroll
    for (int m = 0; m < 4; m++) {
        const u16* pAm = pA + m * 65536;
        const u16* pBm = pB + m * 32768;
        const u16* pCm = pC + m * 16384;
        float biasA_m[4];
        #pragma unroll
        for (int nt = 0; nt < 4; nt++) biasA_m[nt] = bp.ba[m][colA + nt * 16 + l15];
        float biasB_m[2];
        #pragma unroll
        for (int nt = 0; nt < 2; nt++) biasB_m[nt] = bp.bb[m][colC + nt * 16 + l15];

        // ===== stage A: H = relu(A @ Wa + ba) =====
        f32x4 accA[2][4];
        #pragma unroll
        for (int a = 0; a < 2; a++) {
            #pragma unroll
            for (int b = 0; b < 4; b++) accA[a][b] = zero4;
        }
        #pragma unroll
        for (int kk = 0; kk < 8; kk++) {
            short8 w0 = wfA[kk & 1][0], w1 = wfA[kk & 1][1];
            short8 w2 = wfA[kk & 1][2], w3 = wfA[kk & 1][3];
            if (kk < 6) {
                #pragma unroll
                for (int nt = 0; nt < 4; nt++)
                    wfA[kk & 1][nt] = *(const short8*)(pAm + nt * 4096 + (kk + 2) * 32);
            }
            short8 s0, s1, d0, d1;
            if (m != 1) { s0 = *(const short8*)(xsb0 + kk * 32); s1 = *(const short8*)(xsb1 + kk * 32); }
            if (m != 0) { d0 = *(const short8*)(xdb0 + kk * 32); d1 = *(const short8*)(xdb1 + kk * 32); }
            short8 af0, af1;
            if (m == 0)      { af0 = s0; af1 = s1; }
            else if (m == 1) { af0 = d0; af1 = d1; }
            else {
                #pragma unroll
                for (int mt = 0; mt < 2; mt++) {
                    short8 s = mt ? s1 : s0, d = mt ? d1 : d0, rr;
                    #pragma unroll
                    for (int j = 0; j < 8; j++) {
                        float fs = b2f((u16)s[j]);
                        float fd = b2f((u16)d[j]);
                        rr[j] = (short)f2b((m == 2) ? (fs - fd) : (fs * fd));
                    }
                    if (mt) af1 = rr; else af0 = rr;
                }
            }
            accA[0][0] = MFMA16(af0, w0, accA[0][0]);
            accA[1][0] = MFMA16(af1, w0, accA[1][0]);
            accA[0][1] = MFMA16(af0, w1, accA[0][1]);
            accA[1][1] = MFMA16(af1, w1, accA[1][1]);
            accA[0][2] = MFMA16(af0, w2, accA[0][2]);
            accA[1][2] = MFMA16(af1, w2, accA[1][2]);
            accA[0][3] = MFMA16(af0, w3, accA[0][3]);
            accA[1][3] = MFMA16(af1, w3, accA[1][3]);
        }
        // preload B kc=0,1 (land during Hs-write + BARRIER_A)
        short8 wfB[2][2];
        wfB[0][0] = *(const short8*)(pBm);
        wfB[0][1] = *(const short8*)(pBm + 4096);
        wfB[1][0] = *(const short8*)(pBm + 32);
        wfB[1][1] = *(const short8*)(pBm + 4096 + 32);
        #pragma unroll
        for (int nt = 0; nt < 4; nt++) {
            int col = colA + nt * 16 + l15;
            #pragma unroll
            for (int mt = 0; mt < 2; mt++) {
                #pragma unroll
                for (int rg = 0; rg < 4; rg++) {
                    int row = mt * 16 + g * 4 + rg;
                    Hs[row][col] = f2b(fmaxf(accA[mt][nt][rg] + biasA_m[nt], 0.f));
                }
            }
        }
        __syncthreads();                         // BARRIER_A: Hs ready

        // ===== stage B: G = relu(H @ Wb + bb) =====
        f32x4 accB[2][2];
        #pragma unroll
        for (int a = 0; a < 2; a++) {
            #pragma unroll
            for (int b = 0; b < 2; b++) accB[a][b] = zero4;
        }
        #pragma unroll
        for (int kc = 0; kc < 8; kc++) {
            short8 w0 = wfB[kc & 1][0], w1 = wfB[kc & 1][1];
            if (kc < 6) {
                wfB[kc & 1][0] = *(const short8*)(pBm + (kc + 2) * 32);
                wfB[kc & 1][1] = *(const short8*)(pBm + 4096 + (kc + 2) * 32);
            }
            short8 hf0 = *(const short8*)(hgb0 + kc * 32);
            short8 hf1 = *(const short8*)(hgb1 + kc * 32);
            accB[0][0] = MFMA16(hf0, w0, accB[0][0]);
            accB[1][0] = MFMA16(hf1, w0, accB[1][0]);
            accB[0][1] = MFMA16(hf0, w1, accB[0][1]);
            accB[1][1] = MFMA16(hf1, w1, accB[1][1]);
        }
        // preload C cc=0,1 (land during BARRIER_B2 + G-write + BARRIER_B)
        short8 wfC[2][2];
        wfC[0][0] = *(const short8*)(pCm);
        wfC[0][1] = *(const short8*)(pCm + 2048);
        wfC[1][0] = *(const short8*)(pCm + 32);
        wfC[1][1] = *(const short8*)(pCm + 2048 + 32);
        __syncthreads();                         // BARRIER_B2: all H reads done
        #pragma unroll
        for (int nt = 0; nt < 2; nt++) {
            int col = colC + nt * 16 + l15;      // 0..127: G overlays Hs
            #pragma unroll
            for (int mt = 0; mt < 2; mt++) {
                #pragma unroll
                for (int rg = 0; rg < 4; rg++) {
                    int row = mt * 16 + g * 4 + rg;
                    Hs[row][col] = f2b(fmaxf(accB[mt][nt][rg] + biasB_m[nt], 0.f));
                }
            }
        }
        __syncthreads();                         // BARRIER_B: G ready

        // ===== stage C: Facc += G @ WfT_m =====
        #pragma unroll
        for (int cc = 0; cc < 4; cc++) {
            short8 w0 = wfC[cc & 1][0], w1 = wfC[cc & 1][1];
            if (cc < 2) {
                wfC[cc & 1][0] = *(const short8*)(pCm + (cc + 2) * 32);
                wfC[cc & 1][1] = *(const short8*)(pCm + 2048 + (cc + 2) * 32);
            }
            short8 gf0 = *(const short8*)(hgb0 + cc * 32);
            short8 gf1 = *(const short8*)(hgb1 + cc * 32);
            Facc[0][0] = MFMA16(gf0, w0, Facc[0][0]);
            Facc[1][0] = MFMA16(gf1, w0, Facc[1][0]);
            Facc[0][1] = MFMA16(gf0, w1, Facc[0][1]);
            Facc[1][1] = MFMA16(gf1, w1, Facc[1][1]);
        }
        if (m < 3) {
            // preload A(m+1) kk=0,1 (land during BARRIER_C)
            #pragma unroll
            for (int nt = 0; nt < 4; nt++)
                wfA[0][nt] = *(const short8*)(pAm + 65536 + nt * 4096);
            #pragma unroll
            for (int nt = 0; nt < 4; nt++)
                wfA[1][nt] = *(const short8*)(pAm + 65536 + nt * 4096 + 32);
            __syncthreads();                     // BARRIER_C: G reads done before Hs(m+1) writes
        }
    }

    // ===== edge_attr contribution (loaded here; latency hidden once per block) =====
    short8 eaA0, eaA1, eaB0, eaB1;
    float epi_b[2], epi_w[2];
    {
        const float* er0 = ea + (size_t)(e0 + l15) * 32 + g * 8;
        const float* er1 = ea + (size_t)(e0 + 16 + l15) * 32 + g * 8;
        f32x4 a0 = *(const f32x4*)(er0);
        f32x4 b0 = *(const f32x4*)(er0 + 4);
        f32x4 a1 = *(const f32x4*)(er1);
        f32x4 b1 = *(const f32x4*)(er1 + 4);
        eaA0 = pack8(a0, b0);
        eaA1 = pack8(a1, b1);
        eaB0 = *(const short8*)(ws + OFF_WE + (colC + l15) * 32 + g * 8);
        eaB1 = *(const short8*)(ws + OFF_WE + (colC + 16 + l15) * 32 + g * 8);
        epi_b[0] = bfp[colC + l15];
        epi_b[1] = bfp[colC + 16 + l15];
        epi_w[0] = b2f(ws[OFF_WS + colC + l15]);
        epi_w[1] = b2f(ws[OFF_WS + colC + 16 + l15]);
    }
    Facc[0][0] = MFMA16(eaA0, eaB0, Facc[0][0]);
    Facc[1][0] = MFMA16(eaA1, eaB0, Facc[1][0]);
    Facc[0][1] = MFMA16(eaA0, eaB1, Facc[0][1]);
    Facc[1][1] = MFMA16(eaA1, eaB1, Facc[1][1]);

    // ===== epilogue: + s*Wf[512] + bf, tanh, stage f32 in LDS, coalesced store =====
    float* os = (float*)&Xs[0][0];   // reuse Xs: 32 x 132 f32 = 16896 B (exact fit)
    #pragma unroll
    for (int nt = 0; nt < 2; nt++) {
        int col = colC + nt * 16 + l15;
        #pragma unroll
        for (int mt = 0; mt < 2; mt++) {
            #pragma unroll
            for (int rg = 0; rg < 4; rg++) {
                int row = mt * 16 + g * 4 + rg;
                float v = Facc[mt][nt][rg] + scos[row] * epi_w[nt] + epi_b[nt];
                v = fminf(fmaxf(v, -15.f), 15.f);
                float e2 = __expf(2.f * v);
                os[row * 132 + col] = (e2 - 1.f) / (e2 + 1.f);
            }
        }
    }
    __syncthreads();
    {
        int row = t >> 3, c = t & 7;
        float* op = out + (size_t)(e0 + row) * 128 + c * 16;
        const float* sp = os + row * 132 + c * 16;
        #pragma unroll
        for (int i = 0; i < 4; i++) {
            f32x4 v = *(const f32x4*)(sp + i * 4);
            *(f32x4*)(op + i * 4) = v;
        }
    }
}

extern "C" void kernel_launch(void* const* d_in, const int* in_sizes, int n_in,
                              void* d_out, int out_size, void* d_ws, size_t ws_size,
                              hipStream_t stream) {
    u16* ws = (u16*)d_ws;
    prep_kernel<<<dim3(18, 9), 256, 0, stream>>>(
        (const float*)d_in[3],  (const float*)d_in[7],  (const float*)d_in[11], (const float*)d_in[15],
        (const float*)d_in[5],  (const float*)d_in[9],  (const float*)d_in[13], (const float*)d_in[17],
        (const float*)d_in[19], ws);

    BiasP bp;
    bp.ba[0] = (const float*)d_in[4];  bp.ba[1] = (const float*)d_in[8];
    bp.ba[2] = (const float*)d_in[12]; bp.ba[3] = (const float*)d_in[16];
    bp.bb[0] = (const float*)d_in[6];  bp.bb[1] = (const float*)d_in[10];
    bp.bb[2] = (const float*)d_in[14]; bp.bb[3] = (const float*)d_in[18];

    fused_kernel<<<NE / 32, 256, 0, stream>>>(
        (const float*)d_in[0], (const int*)d_in[1], (const float*)d_in[2], ws,
        bp, (const float*)d_in[20], (float*)d_out);
}

// Round 5
// 421.496 us; speedup vs baseline: 1.4064x; 1.4064x over previous
//
#include <hip/hip_runtime.h>
#include <hip/hip_bf16.h>

typedef unsigned short u16;
typedef __attribute__((ext_vector_type(8))) short short8;
typedef __attribute__((ext_vector_type(4))) float f32x4;

#define NE 131072

// ws layout in u16 elements (bf16 transposed weights, [n][k] row-major)
#define OFF_WA 0        // 4 x [256][256]
#define OFF_WB 262144   // 4 x [128][256]
#define OFF_WF 393216   // 4 x [128][128]
#define OFF_WE 458752   // [128][32]
#define OFF_WS 462848   // [128]

// async global->LDS, 16B per lane, lane i lands at lds_base + 16*i
#define ASYNC16(gp, lp) __builtin_amdgcn_global_load_lds( \
    (const __attribute__((address_space(1))) unsigned int*)(gp), \
    (__attribute__((address_space(3))) unsigned int*)(lp), 16, 0, 0)
// wait lgkmcnt(0) only: ds_read data in VGPRs before we re-DMA that LDS slot.
#define LGKM0() __builtin_amdgcn_s_waitcnt(0xC07F)
// counted waits for the 3-deep chunk pipeline (2 loads per chunk).
#define WAIT4() asm volatile("s_waitcnt vmcnt(4)" ::: "memory")
#define WAIT2() asm volatile("s_waitcnt vmcnt(2)" ::: "memory")
#define WAIT0() asm volatile("s_waitcnt vmcnt(0)" ::: "memory")
// non-draining barrier: cross-wave data moves only through LDS (ds ops), so
// lgkmcnt(0) + s_barrier is sufficient; the weight DMA (vmcnt) is wave-private
// and intentionally stays in flight across the barrier (T4: never drain).
#define BAR() asm volatile("s_waitcnt lgkmcnt(0)\n\ts_barrier" ::: "memory")

__device__ __forceinline__ float b2f(u16 v) {
    unsigned int u = ((unsigned int)v) << 16;
    float f;
    __builtin_memcpy(&f, &u, 4);
    return f;
}
__device__ __forceinline__ u16 f2b(float f) {
    __hip_bfloat16 h = __float2bfloat16(f);
    u16 u;
    __builtin_memcpy(&u, &h, 2);
    return u;
}
__device__ __forceinline__ short8 pack8(f32x4 a, f32x4 b) {
    short8 p;
    p[0] = (short)f2b(a.x); p[1] = (short)f2b(a.y);
    p[2] = (short)f2b(a.z); p[3] = (short)f2b(a.w);
    p[4] = (short)f2b(b.x); p[5] = (short)f2b(b.y);
    p[6] = (short)f2b(b.z); p[7] = (short)f2b(b.w);
    return p;
}

#define MFMA16(a, b, c) __builtin_amdgcn_mfma_f32_16x16x32_bf16(a, b, c, 0, 0, 0)

struct BiasP {
    const float* ba[4];
    const float* bb[4];
};

// ---- uniform 2-KB weight chunks, wave-private 3-slot rotation ----
// Chunk = [32 weight rows][32 k] bf16 = 2 KB = 2 global_load_lds. Per block:
// per m-group 28 chunks (A: 16 = 8 kk x 2 col-halves, B: 8, C: 4) -> 112.
// Chunk gc lives in slot (gc % 3) of the wave's 6-KB third. k-slot is
// XOR-swizzled by the same function on DMA source and LDS read.
__device__ __forceinline__ void issue_chunk(const u16* __restrict__ ws, u16* Wb,
                                            int wave, int lane, int gc) {
    if (gc >= 112) return;
    const int m = gc / 28;
    const int c = gc - m * 28;
    const int r = lane >> 2;                        // row 0..15 within 16-row group
    const int slot = (lane & 3) ^ ((lane >> 3) & 3); // pre-swizzled k-slot
    u16* lp = Wb + wave * 3072 + (gc % 3) * 1024;
    const u16* gp;
    int rstride;
    if (c < 16) {            // stage A: Wa_m [256][256], wave cols = wave*64 + (c&1)*32
        int kk = c >> 1, nh = c & 1;
        gp = ws + OFF_WA + m * 65536
           + (size_t)(wave * 64 + nh * 32 + r) * 256 + kk * 32 + slot * 8;
        rstride = 16 * 256;
    } else if (c < 24) {     // stage B: Wb_m [128][256], wave cols = wave*32
        int kc = c - 16;
        gp = ws + OFF_WB + m * 32768
           + (size_t)(wave * 32 + r) * 256 + kc * 32 + slot * 8;
        rstride = 16 * 256;
    } else {                 // stage C: Wf_m [128][128]
        int cc = c - 24;
        gp = ws + OFF_WF + m * 16384
           + (size_t)(wave * 32 + r) * 128 + cc * 32 + slot * 8;
        rstride = 16 * 128;
    }
    ASYNC16(gp, lp);
    ASYNC16(gp + rstride, lp + 512);
}

// LDS-tiled transpose prep: coalesced reads AND writes.
__global__ __launch_bounds__(256)
void prep_kernel(const float* __restrict__ W1a, const float* __restrict__ W2a,
                 const float* __restrict__ W3a, const float* __restrict__ W4a,
                 const float* __restrict__ W1b, const float* __restrict__ W2b,
                 const float* __restrict__ W3b, const float* __restrict__ W4b,
                 const float* __restrict__ Wf,  u16* __restrict__ ws) {
    __shared__ __align__(16) u16 T[64 * 80];

    const int y = blockIdx.y;
    const int t = threadIdx.x;
    const float* in;
    int K, N;
    if (y < 4)      { in = (y == 0) ? W1a : (y == 1) ? W2a : (y == 2) ? W3a : W4a; K = 256; N = 256; }
    else if (y < 8) { in = (y == 4) ? W1b : (y == 5) ? W2b : (y == 6) ? W3b : W4b; K = 256; N = 128; }
    else            { in = Wf; K = 545; N = 128; }

    const int ntilesN = N / 64;
    const int ktiles = (K + 63) / 64;
    const int kt = blockIdx.x / ntilesN;
    const int nt = blockIdx.x - kt * ntilesN;
    if (kt >= ktiles) return;
    const int kbase = kt * 64, nbase = nt * 64;

    {
        int tn = (t & 15) * 4;
        int tk = t >> 4;
        #pragma unroll
        for (int r = 0; r < 4; r++) {
            int k = kbase + tk + 16 * r;
            if (k < K) {
                float4 v = *(const float4*)(in + (size_t)k * N + nbase + tn);
                T[(tn + 0) * 80 + tk + 16 * r] = f2b(v.x);
                T[(tn + 1) * 80 + tk + 16 * r] = f2b(v.y);
                T[(tn + 2) * 80 + tk + 16 * r] = f2b(v.z);
                T[(tn + 3) * 80 + tk + 16 * r] = f2b(v.w);
            }
        }
    }
    __syncthreads();
    {
        int n = t >> 2;
        int kc = (t & 3) * 16;
        int n_out = nbase + n;
        const u16* src = &T[n * 80 + kc];
        if (y < 4) {
            u16* dst = ws + OFF_WA + y * 65536 + (size_t)n_out * 256 + kbase + kc;
            *(short8*)dst = *(const short8*)src;
            *(short8*)(dst + 8) = *(const short8*)(src + 8);
        } else if (y < 8) {
            u16* dst = ws + OFF_WB + (y - 4) * 32768 + (size_t)n_out * 256 + kbase + kc;
            *(short8*)dst = *(const short8*)src;
            *(short8*)(dst + 8) = *(const short8*)(src + 8);
        } else if (kbase < 512) {
            u16* dst = ws + OFF_WF + (kbase >> 7) * 16384 + (size_t)n_out * 128 + (kbase & 127) + kc;
            *(short8*)dst = *(const short8*)src;
            *(short8*)(dst + 8) = *(const short8*)(src + 8);
        } else {
            #pragma unroll
            for (int j = 0; j < 16; j++) {
                int k = kbase + kc + j;
                if (k < 545) {
                    u16 v = src[j];
                    if (k == 512)      ws[OFF_WS + n_out] = v;
                    else               ws[OFF_WE + n_out * 32 + (k - 513)] = v;
                }
            }
        }
    }
}

// 32 edges/block, 4 waves, ~75 KB LDS -> 2 blocks/CU.
// Depth-3 counted-vmcnt weight pipeline with NON-DRAINING stage barriers
// (lgkmcnt(0)+s_barrier): weight DMA stays in flight across every barrier.
// G overlays Hs cols 0..127. Barrier/hazard order per m:
//   A reads Xs/Xd, writes Hs | BAR_A | B reads Hs | BAR_B2 |
//   G-write (Hs cols<128)    | BAR_B | C reads G  | BAR_C (m<3) |
// Epilogue os overlays Xs (last Xs read is A(3), fenced by BAR_A(3)).
__global__ __launch_bounds__(256, 2)
void fused_kernel(const float* __restrict__ x, const int* __restrict__ ei,
                  const float* __restrict__ ea, const u16* __restrict__ ws,
                  BiasP bp, const float* __restrict__ bfp, float* __restrict__ out) {
    __shared__ __align__(16) u16 Xs[32][264];
    __shared__ __align__(16) u16 Xd[32][264];
    __shared__ __align__(16) u16 Hs[32][264];   // cols 0..127 double as G
    __shared__ __align__(16) u16 Wb[12288];     // 24 KB, 6-KB third per wave (3 slots)
    __shared__ float scos[32];

    const int t = threadIdx.x;
    const int wave = t >> 6;
    const int lane = t & 63;
    const int l15 = lane & 15;
    const int g = lane >> 4;
    const int e0 = blockIdx.x * 32;
    const f32x4 zero4 = {0.f, 0.f, 0.f, 0.f};
    const int colA = wave * 64;
    const int colC = wave * 32;

    // Hedge: detect int64 edge_index (sampled high words all zero) vs int32.
    bool idx64 = true;
    #pragma unroll
    for (int i = 1; i < 16; i += 2) { idx64 = idx64 && (ei[i] == 0); }

    // ---- hoisted constants FIRST (older vmcnt entries retire before waits) ----
    short8 eaA[2];
    #pragma unroll
    for (int mt = 0; mt < 2; mt++) {
        const float* er = ea + (size_t)(e0 + mt * 16 + l15) * 32 + g * 8;
        f32x4 a = *(const f32x4*)(er);
        f32x4 b = *(const f32x4*)(er + 4);
        eaA[mt] = pack8(a, b);
    }
    short8 eaB[2];
    float epi_b[2], epi_w[2];
    #pragma unroll
    for (int nt = 0; nt < 2; nt++) {
        int col = colC + nt * 16 + l15;
        eaB[nt] = *(const short8*)(ws + OFF_WE + col * 32 + g * 8);
        epi_b[nt] = bfp[col];
        epi_w[nt] = b2f(ws[OFF_WS + col]);
    }
    float biasA[4][4], biasB[4][2];
    #pragma unroll
    for (int m = 0; m < 4; m++) {
        #pragma unroll
        for (int nt = 0; nt < 4; nt++) biasA[m][nt] = bp.ba[m][colA + nt * 16 + l15];
        #pragma unroll
        for (int nt = 0; nt < 2; nt++) biasB[m][nt] = bp.bb[m][colC + nt * 16 + l15];
    }

    // prime the 3-deep pipeline; chunks land during the gather
    issue_chunk(ws, Wb, wave, lane, 0);
    issue_chunk(ws, Wb, wave, lane, 1);
    issue_chunk(ws, Wb, wave, lane, 2);

    // ---- gather (f32 -> bf16 tiles) + cosine similarity in one pass ----
    {
        int edge = t >> 3;
        int c = t & 7;
        int pos = e0 + edge;
        int is = idx64 ? ei[2 * pos] : ei[pos];
        int id = idx64 ? ei[2 * (NE + pos)] : ei[NE + pos];
        const float* rs = x + (size_t)is * 256 + c * 32;
        const float* rd = x + (size_t)id * 256 + c * 32;
        float dot = 0.f, ss = 0.f, dd = 0.f;
        #pragma unroll
        for (int i = 0; i < 4; i++) {
            f32x4 s0 = *(const f32x4*)(rs + i * 8);
            f32x4 s1 = *(const f32x4*)(rs + i * 8 + 4);
            f32x4 d0 = *(const f32x4*)(rd + i * 8);
            f32x4 d1 = *(const f32x4*)(rd + i * 8 + 4);
            dot += s0.x * d0.x + s0.y * d0.y + s0.z * d0.z + s0.w * d0.w
                 + s1.x * d1.x + s1.y * d1.y + s1.z * d1.z + s1.w * d1.w;
            ss  += s0.x * s0.x + s0.y * s0.y + s0.z * s0.z + s0.w * s0.w
                 + s1.x * s1.x + s1.y * s1.y + s1.z * s1.z + s1.w * s1.w;
            dd  += d0.x * d0.x + d0.y * d0.y + d0.z * d0.z + d0.w * d0.w
                 + d1.x * d1.x + d1.y * d1.y + d1.z * d1.z + d1.w * d1.w;
            *(short8*)(&Xs[edge][c * 32 + i * 8]) = pack8(s0, s1);
            *(short8*)(&Xd[edge][c * 32 + i * 8]) = pack8(d0, d1);
        }
        dot += __shfl_xor(dot, 1); ss += __shfl_xor(ss, 1); dd += __shfl_xor(dd, 1);
        dot += __shfl_xor(dot, 2); ss += __shfl_xor(ss, 2); dd += __shfl_xor(dd, 2);
        dot += __shfl_xor(dot, 4); ss += __shfl_xor(ss, 4); dd += __shfl_xor(dd, 4);
        if (c == 0) {
            float ns = fmaxf(sqrtf(ss), 1e-8f);
            float nd = fmaxf(sqrtf(dd), 1e-8f);
            scos[edge] = dot / (ns * nd);
        }
    }
    BAR();             // gather barrier: Xs/Xd/scos visible; DMA stays in flight

    // ---- LDS read base pointers ----
    const u16* xsb0 = &Xs[l15][g * 8];      const u16* xsb1 = &Xs[16 + l15][g * 8];
    const u16* xdb0 = &Xd[l15][g * 8];      const u16* xdb1 = &Xd[16 + l15][g * 8];
    const u16* hgb0 = &Hs[l15][g * 8];      const u16* hgb1 = &Hs[16 + l15][g * 8];
    // weight frag base: row = nt*16 + l15, k-slot g XOR-swizzled by (l15>>1)&3
    const u16* wbase = Wb + wave * 3072 + l15 * 32 + ((g ^ ((l15 >> 1) & 3)) * 8);

    f32x4 Facc[2][2];
    #pragma unroll
    for (int a = 0; a < 2; a++) {
        #pragma unroll
        for (int b = 0; b < 2; b++) Facc[a][b] = zero4;
    }

    #pragma unroll
    for (int m = 0; m < 4; m++) {
        // ===== stage A: H = relu(A @ Wa + ba) ===== (16 chunks: 8 kk x 2 col-halves)
        f32x4 accA[2][4];
        #pragma unroll
        for (int a = 0; a < 2; a++) {
            #pragma unroll
            for (int b = 0; b < 4; b++) accA[a][b] = zero4;
        }
        #pragma unroll
        for (int kk = 0; kk < 8; kk++) {
            const int gc = m * 28 + kk * 2;
            // X frags first (stable LDS, independent of DMA wait)
            short8 s0, s1, d0, d1;
            if (m != 1) { s0 = *(const short8*)(xsb0 + kk * 32); s1 = *(const short8*)(xsb1 + kk * 32); }
            if (m != 0) { d0 = *(const short8*)(xdb0 + kk * 32); d1 = *(const short8*)(xdb1 + kk * 32); }
            // ---- chunk gc (col-half 0) ----
            WAIT4();
            const u16* wq0 = wbase + (gc % 3) * 1024;
            short8 wf0 = *(const short8*)(wq0);
            short8 wf1 = *(const short8*)(wq0 + 512);
            LGKM0();
            issue_chunk(ws, Wb, wave, lane, gc + 3);
            short8 af0, af1;
            if (m == 0)      { af0 = s0; af1 = s1; }
            else if (m == 1) { af0 = d0; af1 = d1; }
            else {
                #pragma unroll
                for (int mt = 0; mt < 2; mt++) {
                    short8 s = mt ? s1 : s0, d = mt ? d1 : d0, rr;
                    #pragma unroll
                    for (int j = 0; j < 8; j++) {
                        float fs = b2f((u16)s[j]);
                        float fd = b2f((u16)d[j]);
                        rr[j] = (short)f2b((m == 2) ? (fs - fd) : (fs * fd));
                    }
                    if (mt) af1 = rr; else af0 = rr;
                }
            }
            accA[0][0] = MFMA16(af0, wf0, accA[0][0]);
            accA[1][0] = MFMA16(af1, wf0, accA[1][0]);
            accA[0][1] = MFMA16(af0, wf1, accA[0][1]);
            accA[1][1] = MFMA16(af1, wf1, accA[1][1]);
            // ---- chunk gc+1 (col-half 1) ----
            WAIT4();
            const u16* wq1 = wbase + ((gc + 1) % 3) * 1024;
            short8 wf2 = *(const short8*)(wq1);
            short8 wf3 = *(const short8*)(wq1 + 512);
            LGKM0();
            issue_chunk(ws, Wb, wave, lane, gc + 4);
            accA[0][2] = MFMA16(af0, wf2, accA[0][2]);
            accA[1][2] = MFMA16(af1, wf2, accA[1][2]);
            accA[0][3] = MFMA16(af0, wf3, accA[0][3]);
            accA[1][3] = MFMA16(af1, wf3, accA[1][3]);
        }
        #pragma unroll
        for (int nt = 0; nt < 4; nt++) {
            int col = colA + nt * 16 + l15;
            #pragma unroll
            for (int mt = 0; mt < 2; mt++) {
                #pragma unroll
                for (int rg = 0; rg < 4; rg++) {
                    int row = mt * 16 + g * 4 + rg;
                    Hs[row][col] = f2b(fmaxf(accA[mt][nt][rg] + biasA[m][nt], 0.f));
                }
            }
        }
        BAR();                                   // BAR_A: Hs ready (DMA in flight)

        // ===== stage B: G = relu(H @ Wb + bb) ===== (8 chunks of 32-k)
        f32x4 accB[2][2];
        #pragma unroll
        for (int a = 0; a < 2; a++) {
            #pragma unroll
            for (int b = 0; b < 2; b++) accB[a][b] = zero4;
        }
        #pragma unroll
        for (int kc = 0; kc < 8; kc++) {
            const int gc = m * 28 + 16 + kc;
            short8 hf0 = *(const short8*)(hgb0 + kc * 32);
            short8 hf1 = *(const short8*)(hgb1 + kc * 32);
            WAIT4();
            const u16* wq = wbase + (gc % 3) * 1024;
            short8 wf0 = *(const short8*)(wq);
            short8 wf1 = *(const short8*)(wq + 512);
            LGKM0();
            issue_chunk(ws, Wb, wave, lane, gc + 3);
            accB[0][0] = MFMA16(hf0, wf0, accB[0][0]);
            accB[1][0] = MFMA16(hf1, wf0, accB[1][0]);
            accB[0][1] = MFMA16(hf0, wf1, accB[0][1]);
            accB[1][1] = MFMA16(hf1, wf1, accB[1][1]);
        }
        BAR();                                   // BAR_B2: all H reads done
        #pragma unroll
        for (int nt = 0; nt < 2; nt++) {
            int col = colC + nt * 16 + l15;      // cols 0..127: G overlays Hs
            #pragma unroll
            for (int mt = 0; mt < 2; mt++) {
                #pragma unroll
                for (int rg = 0; rg < 4; rg++) {
                    int row = mt * 16 + g * 4 + rg;
                    Hs[row][col] = f2b(fmaxf(accB[mt][nt][rg] + biasB[m][nt], 0.f));
                }
            }
        }
        BAR();                                   // BAR_B: G ready

        // ===== stage C: Facc += G @ WfT_m ===== (4 chunks of 32-k)
        #pragma unroll
        for (int cc = 0; cc < 4; cc++) {
            const int gc = m * 28 + 24 + cc;
            short8 gf0 = *(const short8*)(hgb0 + cc * 32);
            short8 gf1 = *(const short8*)(hgb1 + cc * 32);
            // tail ramp-down: at gc=110 only {110,111} outstanding; at 111 only {111}
            if (m == 3 && cc == 2)      { WAIT2(); }
            else if (m == 3 && cc == 3) { WAIT0(); }
            else                        { WAIT4(); }
            const u16* wq = wbase + (gc % 3) * 1024;
            short8 wf0 = *(const short8*)(wq);
            short8 wf1 = *(const short8*)(wq + 512);
            LGKM0();
            issue_chunk(ws, Wb, wave, lane, gc + 3);
            Facc[0][0] = MFMA16(gf0, wf0, Facc[0][0]);
            Facc[1][0] = MFMA16(gf1, wf0, Facc[1][0]);
            Facc[0][1] = MFMA16(gf0, wf1, Facc[0][1]);
            Facc[1][1] = MFMA16(gf1, wf1, Facc[1][1]);
        }
        if (m < 3) BAR();                        // BAR_C: G reads done before Hs(m+1) writes
    }

    // ===== edge_attr contribution (fragments pre-loaded) =====
    #pragma unroll
    for (int mt = 0; mt < 2; mt++) {
        #pragma unroll
        for (int nt = 0; nt < 2; nt++) {
            Facc[mt][nt] = MFMA16(eaA[mt], eaB[nt], Facc[mt][nt]);
        }
    }

    // ===== epilogue: + s*Wf[512] + bf, tanh, stage f32 in LDS, coalesced store =====
    float* os = (float*)&Xs[0][0];   // reuse Xs: 32 x 132 f32 = 16896 B (exact fit)
    #pragma unroll
    for (int nt = 0; nt < 2; nt++) {
        int col = colC + nt * 16 + l15;
        #pragma unroll
        for (int mt = 0; mt < 2; mt++) {
            #pragma unroll
            for (int rg = 0; rg < 4; rg++) {
                int row = mt * 16 + g * 4 + rg;
                float v = Facc[mt][nt][rg] + scos[row] * epi_w[nt] + epi_b[nt];
                v = fminf(fmaxf(v, -15.f), 15.f);
                float e2 = __expf(2.f * v);
                os[row * 132 + col] = (e2 - 1.f) / (e2 + 1.f);
            }
        }
    }
    BAR();
    {
        int row = t >> 3, c = t & 7;
        float* op = out + (size_t)(e0 + row) * 128 + c * 16;
        const float* sp = os + row * 132 + c * 16;
        #pragma unroll
        for (int i = 0; i < 4; i++) {
            f32x4 v = *(const f32x4*)(sp + i * 4);
            *(f32x4*)(op + i * 4) = v;
        }
    }
}

extern "C" void kernel_launch(void* const* d_in, const int* in_sizes, int n_in,
                              void* d_out, int out_size, void* d_ws, size_t ws_size,
                              hipStream_t stream) {
    u16* ws = (u16*)d_ws;
    prep_kernel<<<dim3(18, 9), 256, 0, stream>>>(
        (const float*)d_in[3],  (const float*)d_in[7],  (const float*)d_in[11], (const float*)d_in[15],
        (const float*)d_in[5],  (const float*)d_in[9],  (const float*)d_in[13], (const float*)d_in[17],
        (const float*)d_in[19], ws);

    BiasP bp;
    bp.ba[0] = (const float*)d_in[4];  bp.ba[1] = (const float*)d_in[8];
    bp.ba[2] = (const float*)d_in[12]; bp.ba[3] = (const float*)d_in[16];
    bp.bb[0] = (const float*)d_in[6];  bp.bb[1] = (const float*)d_in[10];
    bp.bb[2] = (const float*)d_in[14]; bp.bb[3] = (const float*)d_in[18];

    fused_kernel<<<NE / 32, 256, 0, stream>>>(
        (const float*)d_in[0], (const int*)d_in[1], (const float*)d_in[2], ws,
        bp, (const float*)d_in[20], (float*)d_out);
}